// Round 1
// baseline (114.452 us; speedup 1.0000x reference)
//
#include <hip/hip_runtime.h>
#include <hip/hip_bf16.h>

// ---- problem constants ----
#define NF     1044
#define NFP    1056                 // fields padded to mult of 32 (nice K tiling)
#define FD     9
#define VOCP   (NFP*FD)             // 9504 padded vocab
#define KTOT   (NFP*4)              // 4224 padded K
#define BATCH  16384
#define NCHUNK 33                   // 4224 / 128
#define CHUNK_B 8192                // bytes of bf16 w1 fragments per 128-k chunk

typedef float f32x4 __attribute__((ext_vector_type(4)));
typedef short s16x8 __attribute__((ext_vector_type(8)));
typedef short s16x4 __attribute__((ext_vector_type(4)));

// ---- workspace layout (bytes) ----
#define WS_EMB8  0u          // bf16 emb, 9504*4*2 = 76032
#define WS_W1T   76032u      // fragment-major bf16 w1*s1, 33*8192 = 270336
#define WS_W2F   346368u     // fragment-major bf16 w2*s2, 2048
#define WS_B1P   348416u     // f32 b1*s1+be1, 128
#define WS_B2P   348544u     // f32 b2*s2+be2, 128
#define WS_NIB   348672u     // nibble-packed bucket ids, 16384*132*4 = 8650752
#define WS_LIN   8999424u    // f32 lin per row, 65536
// total ~9.07 MB

// fragment slot address inside a chunk for (s,kg,h): s*2048 + kg*512 + h*16,
// shorts within slot: i<4 -> k = 128c+32s+4kg+i ; i>=4 -> k = 128c+32s+16+4kg+(i-4)

__global__ __launch_bounds__(256) void k0_setup(
    const float* __restrict__ emb, const float* __restrict__ w1,
    const float* __restrict__ b1, const float* __restrict__ g1,
    const float* __restrict__ be1, const float* __restrict__ w2,
    const float* __restrict__ b2, const float* __restrict__ g2,
    const float* __restrict__ be2, char* __restrict__ ws) {
  const float inv = 1.0f / sqrtf(1.0f + 1e-5f);
  __hip_bfloat16* emb8 = (__hip_bfloat16*)(ws + WS_EMB8);
  float* b1p = (float*)(ws + WS_B1P);
  float* b2p = (float*)(ws + WS_B2P);
  const int total = 9504 + 135168 + 1024 + 64;
  for (int idx = blockIdx.x * 256 + threadIdx.x; idx < total;
       idx += gridDim.x * 256) {
    if (idx < 9504) {
      int g = idx;
      float4 e = (g < 9396) ? ((const float4*)emb)[g] : make_float4(0.f,0.f,0.f,0.f);
      emb8[g*4+0] = __float2bfloat16(e.x);
      emb8[g*4+1] = __float2bfloat16(e.y);
      emb8[g*4+2] = __float2bfloat16(e.z);
      emb8[g*4+3] = __float2bfloat16(e.w);
    } else if (idx < 9504 + 135168) {
      int m = idx - 9504;
      int h = m / 4224, k = m - h*4224;
      float s1 = g1[h] * inv;
      float v = (k < 4176) ? w1[k*32 + h] * s1 : 0.0f;
      int c = k >> 7, k7 = k & 127;
      int s = k7 >> 5, k32 = k7 & 31;
      int half = k32 >> 4, kk = k32 & 15;
      int kg = kk >> 2, e = kk & 3;
      int off = c*8192 + s*2048 + kg*512 + h*16 + (half*4 + e)*2;
      *(__hip_bfloat16*)(ws + WS_W1T + off) = __float2bfloat16(v);
    } else if (idx < 9504 + 135168 + 1024) {
      int m = idx - (9504 + 135168);
      int h = m >> 5, j = m & 31;
      float s2 = g2[j] * inv;
      float v = w2[h*32 + j] * s2;
      int half = h >> 4, kk = h & 15;
      int kg = kk >> 2, e = kk & 3;
      int off = kg*512 + j*16 + (half*4 + e)*2;
      *(__hip_bfloat16*)(ws + WS_W2F + off) = __float2bfloat16(v);
    } else {
      int m = idx - (9504 + 135168 + 1024);
      if (m < 32)      b1p[m]    = b1[m]*(g1[m]*inv) + be1[m];
      else             b2p[m-32] = b2[m-32]*(g2[m-32]*inv) + be2[m-32];
    }
  }
}

// kernel 1: hash + nibble pack + lin.  grid 1024 x 256, 16 rows/block.
__global__ __launch_bounds__(256) void k1_hash(
    const float* __restrict__ state, const float* __restrict__ wlin,
    const float* __restrict__ blin, char* __restrict__ ws) {
  __shared__ float wl[VOCP];            // 38016 B
  __shared__ unsigned int vbuf[NFP];    // 4224 B
  __shared__ float red[64];
  unsigned int* nib32 = (unsigned int*)(ws + WS_NIB);
  float* ling = (float*)(ws + WS_LIN);
  const int t = threadIdx.x;
  const int wid = t >> 6;
  for (int i = t; i < VOCP; i += 256) wl[i] = (i < 9396) ? wlin[i] : 0.0f;
  __syncthreads();
  for (int r0 = 0; r0 < 16; ++r0) {
    const int row = blockIdx.x*16 + r0;
    float lacc = 0.0f;
    #pragma unroll
    for (int j = 0; j < 5; ++j) {
      int f = t + 256*j;
      if (f < 1044) {
        float s = state[row*1044 + f];
        int v = (s > 5.0f) ? 8 : (int)(s + 2.0f);
        lacc += wl[9*f + v];            // 9-stride -> conflict-light
        vbuf[f] = (unsigned)v;
      } else if (f < NFP) {
        vbuf[f] = 0u;
      }
    }
    __syncthreads();
    if (t < 132) {
      unsigned int pk = 0;
      #pragma unroll
      for (int q = 0; q < 8; ++q) pk |= (vbuf[8*t + q] << (4*q));
      nib32[row*132 + t] = pk;
    }
    #pragma unroll
    for (int m = 1; m < 64; m <<= 1) lacc += __shfl_xor(lacc, m);
    if ((t & 63) == 0) red[r0*4 + wid] = lacc;
    __syncthreads();
  }
  if (t < 16) {
    int row = blockIdx.x*16 + t;
    ling[row] = red[t*4+0] + red[t*4+1] + red[t*4+2] + red[t*4+3] + blin[0];
  }
}

// kernel 2: gather + MFMA MLP.  grid 256 x 256 (4 waves, 16 rows each).
__global__ __launch_bounds__(256) void k2_mlp(
    char* __restrict__ ws, const float* __restrict__ w3g,
    const float* __restrict__ b3g, float* __restrict__ out) {
  __shared__ uint4 w1buf[2][512];                    // 16384 B, double-buffered chunk
  __shared__ __align__(16) unsigned int nibL[64*132];// 33792 B
  __shared__ __align__(16) __hip_bfloat16 h1b[64*40];// 5120 B (stride 40 pads banks)
  __shared__ uint4 w2l4[128];                        // 2048 B
  const int t = threadIdx.x;
  const int lane = t & 63, w = t >> 6;
  const int rowbase = blockIdx.x * 64;

  // stage nibbles for our 64 rows
  const unsigned int* nibg = (const unsigned int*)(ws + WS_NIB) + (size_t)rowbase*132;
  for (int i = t; i < 64*132; i += 256) nibL[i] = nibg[i];
  // stage w2 fragments
  const uint4* w2g4 = (const uint4*)(ws + WS_W2F);
  if (t < 128) w2l4[t] = w2g4[t];
  // stage chunk 0 of w1
  const uint4* w1g4 = (const uint4*)(ws + WS_W1T);
  w1buf[0][t*2]   = w1g4[t*2];
  w1buf[0][t*2+1] = w1g4[t*2+1];
  __syncthreads();

  const int kg = lane >> 4;        // k-group 0..3
  const int h  = lane & 15;
  const int sh0 = 8*(kg >> 1);
  const int nibsel = kg & 1;
  const int nibbase = (w*16 + h)*132;
  const s16x4* E4 = (const s16x4*)ws;   // emb8 at offset 0
  f32x4 acc0 = {0.f,0.f,0.f,0.f}, acc1 = {0.f,0.f,0.f,0.f};

  for (int c = 0; c < NCHUNK; ++c) {
    uint4 st0 = {0,0,0,0}, st1 = {0,0,0,0};
    const bool more = (c + 1 < NCHUNK);
    if (more) {                     // issue next-chunk loads early (hide under MFMA)
      st0 = w1g4[(c+1)*512 + t*2];
      st1 = w1g4[(c+1)*512 + t*2+1];
    }
    const char* wb = (const char*)w1buf[c & 1];
    uint4 nw = *(const uint4*)&nibL[nibbase + c*4];
    unsigned int nwa[4] = {nw.x, nw.y, nw.z, nw.w};
    #pragma unroll
    for (int s = 0; s < 4; ++s) {
      unsigned int W = nwa[s];
      unsigned int bA = (W >> sh0) & 0xFFu;
      unsigned int bB = (W >> (sh0 + 16)) & 0xFFu;
      int vA = nibsel ? (int)(bA >> 4) : (int)(bA & 15u);
      int vB = nibsel ? (int)(bB >> 4) : (int)(bB & 15u);
      int F0 = c*32 + s*8 + kg;
      s16x4 e0 = E4[F0*9 + vA];
      s16x4 e1 = E4[(F0+4)*9 + vB];
      s16x8 a = __builtin_shufflevector(e0, e1, 0,1,2,3,4,5,6,7);
      const s16x8* bp = (const s16x8*)(wb + s*2048 + kg*512);
      s16x8 bf0 = bp[h];
      s16x8 bf1 = bp[h + 16];
      acc0 = __builtin_amdgcn_mfma_f32_16x16x32_bf16(a, bf0, acc0, 0, 0, 0);
      acc1 = __builtin_amdgcn_mfma_f32_16x16x32_bf16(a, bf1, acc1, 0, 0, 0);
    }
    if (more) {
      w1buf[(c+1) & 1][t*2]   = st0;
      w1buf[(c+1) & 1][t*2+1] = st1;
    }
    __syncthreads();
  }

  // epilogue 1: h1 = relu(acc + b1'), store bf16 (C/D: row=(kg*4+reg), col=h)
  const float* b1p = (const float*)(ws + WS_B1P);
  const float bb0 = b1p[h], bb1 = b1p[h + 16];
  #pragma unroll
  for (int reg = 0; reg < 4; ++reg) {
    int r = kg*4 + reg;
    float a0 = acc0[reg] + bb0; a0 = a0 > 0.f ? a0 : 0.f;
    float a1 = acc1[reg] + bb1; a1 = a1 > 0.f ? a1 : 0.f;
    h1b[(w*16 + r)*40 + h]      = __float2bfloat16(a0);
    h1b[(w*16 + r)*40 + h + 16] = __float2bfloat16(a1);
  }
  __syncthreads();

  // layer 2 (MFMA) + layer 3 + sigmoid
  s16x4 alo = *(const s16x4*)&h1b[(w*16 + h)*40 + kg*4];
  s16x4 ahi = *(const s16x4*)&h1b[(w*16 + h)*40 + 16 + kg*4];
  s16x8 a2 = __builtin_shufflevector(alo, ahi, 0,1,2,3,4,5,6,7);
  const char* w2l = (const char*)w2l4;
  const s16x8* w2p8 = (const s16x8*)(w2l + kg*512);
  s16x8 b20 = w2p8[h];
  s16x8 b21 = w2p8[h + 16];
  f32x4 acc20 = {0.f,0.f,0.f,0.f}, acc21 = {0.f,0.f,0.f,0.f};
  acc20 = __builtin_amdgcn_mfma_f32_16x16x32_bf16(a2, b20, acc20, 0, 0, 0);
  acc21 = __builtin_amdgcn_mfma_f32_16x16x32_bf16(a2, b21, acc21, 0, 0, 0);
  const float* b2p = (const float*)(ws + WS_B2P);
  const float c20 = b2p[h], c21 = b2p[h + 16];
  const float w3a = w3g[h], w3b = w3g[h + 16];
  const float* ling = (const float*)(ws + WS_LIN);
  const float b3v = b3g[0];
  #pragma unroll
  for (int reg = 0; reg < 4; ++reg) {
    float h2a = acc20[reg] + c20; h2a = h2a > 0.f ? h2a : 0.f;
    float h2b = acc21[reg] + c21; h2b = h2b > 0.f ? h2b : 0.f;
    float p = h2a*w3a + h2b*w3b;
    p += __shfl_xor(p, 1);
    p += __shfl_xor(p, 2);
    p += __shfl_xor(p, 4);
    p += __shfl_xor(p, 8);
    if (h == 0) {
      int grow = rowbase + w*16 + kg*4 + reg;
      float x = p + ling[grow] + b3v;
      out[grow] = 1.0f / (1.0f + expf(-x));
    }
  }
}

extern "C" void kernel_launch(void* const* d_in, const int* in_sizes, int n_in,
                              void* d_out, int out_size, void* d_ws, size_t ws_size,
                              hipStream_t stream) {
  const float* state = (const float*)d_in[0];
  const float* wlin  = (const float*)d_in[1];
  const float* blin  = (const float*)d_in[2];
  const float* emb   = (const float*)d_in[3];
  const float* w1    = (const float*)d_in[4];
  const float* b1    = (const float*)d_in[5];
  const float* g1    = (const float*)d_in[6];
  const float* be1   = (const float*)d_in[7];
  const float* w2    = (const float*)d_in[8];
  const float* b2    = (const float*)d_in[9];
  const float* g2    = (const float*)d_in[10];
  const float* be2   = (const float*)d_in[11];
  const float* w3    = (const float*)d_in[12];
  const float* b3    = (const float*)d_in[13];
  char* ws = (char*)d_ws;
  float* out = (float*)d_out;

  hipLaunchKernelGGL(k0_setup, dim3(570), dim3(256), 0, stream,
                     emb, w1, b1, g1, be1, w2, b2, g2, be2, ws);
  hipLaunchKernelGGL(k1_hash, dim3(1024), dim3(256), 0, stream,
                     state, wlin, blin, ws);
  hipLaunchKernelGGL(k2_mlp, dim3(256), dim3(256), 0, stream,
                     ws, w3, b3, out);
}

// Round 2
// 54.303 us; speedup vs baseline: 2.1076x; 2.1076x over previous
//
#include <hip/hip_runtime.h>
#include <hip/hip_bf16.h>

// ---- problem constants ----
#define NF     1044
#define NFP    1056                 // fields padded to mult of 32 (nice K tiling)
#define FD     9
#define VOCP   (NFP*FD)             // 9504 padded vocab
#define KTOT   (NFP*4)              // 4224 padded K
#define BATCH  16384
#define NCHUNK 33                   // 4224 / 128
#define CHUNK_B 8192                // bytes of bf16 w1 fragments per 128-k chunk

typedef float f32x4 __attribute__((ext_vector_type(4)));
typedef short s16x8 __attribute__((ext_vector_type(8)));
typedef short s16x4 __attribute__((ext_vector_type(4)));

// ---- workspace layout (bytes) ----
#define WS_EMB8  0u          // bf16 emb, 9504*4*2 = 76032
#define WS_W1T   76032u      // fragment-major bf16 w1*s1, 33*8192 = 270336
#define WS_W2F   346368u     // fragment-major bf16 w2*s2, 2048
#define WS_B1P   348416u     // f32 b1*s1+be1, 128
#define WS_B2P   348544u     // f32 b2*s2+be2, 128
#define WS_NIB   348672u     // nibble-packed bucket ids, 16384*132*4 = 8650752
#define WS_LIN   8999424u    // f32 lin per row, 65536

__global__ __launch_bounds__(256) void k0_setup(
    const float* __restrict__ emb, const float* __restrict__ w1,
    const float* __restrict__ b1, const float* __restrict__ g1,
    const float* __restrict__ be1, const float* __restrict__ w2,
    const float* __restrict__ b2, const float* __restrict__ g2,
    const float* __restrict__ be2, char* __restrict__ ws) {
  const float inv = 1.0f / sqrtf(1.0f + 1e-5f);
  __hip_bfloat16* emb8 = (__hip_bfloat16*)(ws + WS_EMB8);
  float* b1p = (float*)(ws + WS_B1P);
  float* b2p = (float*)(ws + WS_B2P);
  const int total = 9504 + 135168 + 1024 + 64;
  for (int idx = blockIdx.x * 256 + threadIdx.x; idx < total;
       idx += gridDim.x * 256) {
    if (idx < 9504) {
      int g = idx;
      float4 e = (g < 9396) ? ((const float4*)emb)[g] : make_float4(0.f,0.f,0.f,0.f);
      emb8[g*4+0] = __float2bfloat16(e.x);
      emb8[g*4+1] = __float2bfloat16(e.y);
      emb8[g*4+2] = __float2bfloat16(e.z);
      emb8[g*4+3] = __float2bfloat16(e.w);
    } else if (idx < 9504 + 135168) {
      int m = idx - 9504;
      int h = m / 4224, k = m - h*4224;
      float s1 = g1[h] * inv;
      float v = (k < 4176) ? w1[k*32 + h] * s1 : 0.0f;
      int c = k >> 7, k7 = k & 127;
      int s = k7 >> 5, k32 = k7 & 31;
      int half = k32 >> 4, kk = k32 & 15;
      int kg = kk >> 2, e = kk & 3;
      int off = c*8192 + s*2048 + kg*512 + h*16 + (half*4 + e)*2;
      *(__hip_bfloat16*)(ws + WS_W1T + off) = __float2bfloat16(v);
    } else if (idx < 9504 + 135168 + 1024) {
      int m = idx - (9504 + 135168);
      int h = m >> 5, j = m & 31;
      float s2 = g2[j] * inv;
      float v = w2[h*32 + j] * s2;
      int half = h >> 4, kk = h & 15;
      int kg = kk >> 2, e = kk & 3;
      int off = kg*512 + j*16 + (half*4 + e)*2;
      *(__hip_bfloat16*)(ws + WS_W2F + off) = __float2bfloat16(v);
    } else {
      int m = idx - (9504 + 135168 + 1024);
      if (m < 32)      b1p[m]    = b1[m]*(g1[m]*inv) + be1[m];
      else             b2p[m-32] = b2[m-32]*(g2[m-32]*inv) + be2[m-32];
    }
  }
}

// kernel 1: hash + nibble pack + lin.  Barrier-free: one wave per row,
// lane owns words l and 64+l (8 fields each), tail words on lanes 0..3.
// lin pass: lane handles fields l+64j, bucket ids fetched by __shfl from
// the word-owner lane; w_lin gathered from LDS (9l+v mod 32 ~ 2 lanes/bank).
__device__ __forceinline__ unsigned pack8(float4 a, float4 b) {
  float v[8] = {a.x, a.y, a.z, a.w, b.x, b.y, b.z, b.w};
  unsigned pk = 0;
  #pragma unroll
  for (int q = 0; q < 8; ++q) {
    int t = (v[q] > 5.0f) ? 8 : (int)(v[q] + 2.0f);
    pk |= (unsigned)t << (4*q);
  }
  return pk;
}

__global__ __launch_bounds__(256) void k1_hash(
    const float* __restrict__ state, const float* __restrict__ wlin,
    const float* __restrict__ blin, char* __restrict__ ws) {
  __shared__ float wl[9396];            // 37584 B -> 4 blocks/CU
  const int t = threadIdx.x;
  for (int i = t; i < 2349; i += 256)
    ((float4*)wl)[i] = ((const float4*)wlin)[i];
  __syncthreads();

  unsigned int* nib32 = (unsigned int*)(ws + WS_NIB);
  float* ling = (float*)(ws + WS_LIN);
  const int l = t & 63;
  const int gw = (blockIdx.x * 256 + t) >> 6;   // global wave id, 0..4095
  const float bl = blin[0];

  for (int row = gw; row < BATCH; row += 4096) {
    const float4* s4 = (const float4*)(state + (size_t)row * 1044);
    // main words: w=l (fields 8l..8l+7), w=64+l (fields 512+8l..)
    float4 a0 = s4[2*l],     b0 = s4[2*l + 1];
    float4 a1 = s4[128+2*l], b1 = s4[129+2*l];
    float4 zz = make_float4(0.f, 0.f, 0.f, 0.f);
    float4 ta = (l < 3) ? s4[256 + 2*l] : zz;   // words 128,129 full; 130 partial
    float4 tb = (l < 2) ? s4[257 + 2*l] : zz;
    unsigned pk0 = pack8(a0, b0);
    unsigned pk1 = pack8(a1, b1);
    unsigned pk2 = pack8(ta, tb);               // lane>=3: 0x22222222 (padded fields, don't-care)

    unsigned int* nr = nib32 + (size_t)row * 132;
    nr[l]      = pk0;
    nr[64 + l] = pk1;
    if (l < 4) nr[128 + l] = pk2;

    // lin: field f = l + 64j; word a+8j (a=l>>3) owned by lane via shfl
    float lacc = 0.f;
    #pragma unroll
    for (int j = 0; j < 16; ++j) {
      int src = (l >> 3) + 8 * (j & 7);
      unsigned wv = __shfl((j < 8) ? pk0 : pk1, src, 64);
      int v = (wv >> (4 * (l & 7))) & 15;
      lacc += wl[(l + 64*j) * 9 + v];
    }
    if (l < 20) {                                // f = l+1024 < 1044
      unsigned wv = __shfl(pk2, l >> 3, 64);
      int v = (wv >> (4 * (l & 7))) & 15;
      lacc += wl[(l + 1024) * 9 + v];
    }
    #pragma unroll
    for (int m = 1; m < 64; m <<= 1) lacc += __shfl_xor(lacc, m, 64);
    if (l == 0) ling[row] = lacc + bl;
  }
}

// kernel 2: gather + MFMA MLP.  grid 256 x 256 (4 waves, 16 rows each).
__global__ __launch_bounds__(256) void k2_mlp(
    char* __restrict__ ws, const float* __restrict__ w3g,
    const float* __restrict__ b3g, float* __restrict__ out) {
  __shared__ uint4 w1buf[2][512];                    // 16384 B, double-buffered chunk
  __shared__ __align__(16) unsigned int nibL[64*132];// 33792 B
  __shared__ __align__(16) __hip_bfloat16 h1b[64*40];// 5120 B (stride 40 pads banks)
  __shared__ uint4 w2l4[128];                        // 2048 B
  const int t = threadIdx.x;
  const int lane = t & 63, w = t >> 6;
  const int rowbase = blockIdx.x * 64;

  const unsigned int* nibg = (const unsigned int*)(ws + WS_NIB) + (size_t)rowbase*132;
  for (int i = t; i < 64*132; i += 256) nibL[i] = nibg[i];
  const uint4* w2g4 = (const uint4*)(ws + WS_W2F);
  if (t < 128) w2l4[t] = w2g4[t];
  const uint4* w1g4 = (const uint4*)(ws + WS_W1T);
  w1buf[0][t*2]   = w1g4[t*2];
  w1buf[0][t*2+1] = w1g4[t*2+1];
  __syncthreads();

  const int kg = lane >> 4;        // k-group 0..3
  const int h  = lane & 15;
  const int sh0 = 8*(kg >> 1);
  const int nibsel = kg & 1;
  const int nibbase = (w*16 + h)*132;
  const s16x4* E4 = (const s16x4*)ws;   // emb8 at offset 0
  f32x4 acc0 = {0.f,0.f,0.f,0.f}, acc1 = {0.f,0.f,0.f,0.f};

  for (int c = 0; c < NCHUNK; ++c) {
    uint4 st0 = {0,0,0,0}, st1 = {0,0,0,0};
    const bool more = (c + 1 < NCHUNK);
    if (more) {
      st0 = w1g4[(c+1)*512 + t*2];
      st1 = w1g4[(c+1)*512 + t*2+1];
    }
    const char* wb = (const char*)w1buf[c & 1];
    uint4 nw = *(const uint4*)&nibL[nibbase + c*4];
    unsigned int nwa[4] = {nw.x, nw.y, nw.z, nw.w};
    #pragma unroll
    for (int s = 0; s < 4; ++s) {
      unsigned int W = nwa[s];
      unsigned int bA = (W >> sh0) & 0xFFu;
      unsigned int bB = (W >> (sh0 + 16)) & 0xFFu;
      int vA = nibsel ? (int)(bA >> 4) : (int)(bA & 15u);
      int vB = nibsel ? (int)(bB >> 4) : (int)(bB & 15u);
      int F0 = c*32 + s*8 + kg;
      s16x4 e0 = E4[F0*9 + vA];
      s16x4 e1 = E4[(F0+4)*9 + vB];
      s16x8 a = __builtin_shufflevector(e0, e1, 0,1,2,3,4,5,6,7);
      const s16x8* bp = (const s16x8*)(wb + s*2048 + kg*512);
      s16x8 bf0 = bp[h];
      s16x8 bf1 = bp[h + 16];
      acc0 = __builtin_amdgcn_mfma_f32_16x16x32_bf16(a, bf0, acc0, 0, 0, 0);
      acc1 = __builtin_amdgcn_mfma_f32_16x16x32_bf16(a, bf1, acc1, 0, 0, 0);
    }
    if (more) {
      w1buf[(c+1) & 1][t*2]   = st0;
      w1buf[(c+1) & 1][t*2+1] = st1;
    }
    __syncthreads();
  }

  const float* b1p = (const float*)(ws + WS_B1P);
  const float bb0 = b1p[h], bb1 = b1p[h + 16];
  #pragma unroll
  for (int reg = 0; reg < 4; ++reg) {
    int r = kg*4 + reg;
    float a0 = acc0[reg] + bb0; a0 = a0 > 0.f ? a0 : 0.f;
    float a1 = acc1[reg] + bb1; a1 = a1 > 0.f ? a1 : 0.f;
    h1b[(w*16 + r)*40 + h]      = __float2bfloat16(a0);
    h1b[(w*16 + r)*40 + h + 16] = __float2bfloat16(a1);
  }
  __syncthreads();

  s16x4 alo = *(const s16x4*)&h1b[(w*16 + h)*40 + kg*4];
  s16x4 ahi = *(const s16x4*)&h1b[(w*16 + h)*40 + 16 + kg*4];
  s16x8 a2 = __builtin_shufflevector(alo, ahi, 0,1,2,3,4,5,6,7);
  const char* w2l = (const char*)w2l4;
  const s16x8* w2p8 = (const s16x8*)(w2l + kg*512);
  s16x8 b20 = w2p8[h];
  s16x8 b21 = w2p8[h + 16];
  f32x4 acc20 = {0.f,0.f,0.f,0.f}, acc21 = {0.f,0.f,0.f,0.f};
  acc20 = __builtin_amdgcn_mfma_f32_16x16x32_bf16(a2, b20, acc20, 0, 0, 0);
  acc21 = __builtin_amdgcn_mfma_f32_16x16x32_bf16(a2, b21, acc21, 0, 0, 0);
  const float* b2p = (const float*)(ws + WS_B2P);
  const float c20 = b2p[h], c21 = b2p[h + 16];
  const float w3a = w3g[h], w3b = w3g[h + 16];
  const float* ling = (const float*)(ws + WS_LIN);
  const float b3v = b3g[0];
  #pragma unroll
  for (int reg = 0; reg < 4; ++reg) {
    float h2a = acc20[reg] + c20; h2a = h2a > 0.f ? h2a : 0.f;
    float h2b = acc21[reg] + c21; h2b = h2b > 0.f ? h2b : 0.f;
    float p = h2a*w3a + h2b*w3b;
    p += __shfl_xor(p, 1);
    p += __shfl_xor(p, 2);
    p += __shfl_xor(p, 4);
    p += __shfl_xor(p, 8);
    if (h == 0) {
      int grow = rowbase + w*16 + kg*4 + reg;
      float x = p + ling[grow] + b3v;
      out[grow] = 1.0f / (1.0f + expf(-x));
    }
  }
}

extern "C" void kernel_launch(void* const* d_in, const int* in_sizes, int n_in,
                              void* d_out, int out_size, void* d_ws, size_t ws_size,
                              hipStream_t stream) {
  const float* state = (const float*)d_in[0];
  const float* wlin  = (const float*)d_in[1];
  const float* blin  = (const float*)d_in[2];
  const float* emb   = (const float*)d_in[3];
  const float* w1    = (const float*)d_in[4];
  const float* b1    = (const float*)d_in[5];
  const float* g1    = (const float*)d_in[6];
  const float* be1   = (const float*)d_in[7];
  const float* w2    = (const float*)d_in[8];
  const float* b2    = (const float*)d_in[9];
  const float* g2    = (const float*)d_in[10];
  const float* be2   = (const float*)d_in[11];
  const float* w3    = (const float*)d_in[12];
  const float* b3    = (const float*)d_in[13];
  char* ws = (char*)d_ws;
  float* out = (float*)d_out;

  hipLaunchKernelGGL(k0_setup, dim3(570), dim3(256), 0, stream,
                     emb, w1, b1, g1, be1, w2, b2, g2, be2, ws);
  hipLaunchKernelGGL(k1_hash, dim3(1024), dim3(256), 0, stream,
                     state, wlin, blin, ws);
  hipLaunchKernelGGL(k2_mlp, dim3(256), dim3(256), 0, stream,
                     ws, w3, b3, out);
}

// Round 4
// 40.283 us; speedup vs baseline: 2.8412x; 1.3480x over previous
//
#include <hip/hip_runtime.h>
#include <hip/hip_bf16.h>

// ---- problem constants ----
#define NF     1044
#define NFP    1088                 // fields padded to 34*32 (even chunk count)
#define FD     9
#define VOCP   (NFP*FD)             // 9792 padded vocab rows
#define KTOT   (NFP*4)              // 4352
#define BATCH  16384
#define NCHUNK 34                   // 4352 / 128  (even -> clean parity split)
#define NWORD  136                  // nibble words per row (1088/8)

typedef float f32x4 __attribute__((ext_vector_type(4)));
typedef short s16x8 __attribute__((ext_vector_type(8)));
typedef short s16x4 __attribute__((ext_vector_type(4)));

static __device__ __forceinline__ unsigned short bf16bits(float v) {
  return __builtin_bit_cast(unsigned short, __float2bfloat16(v));
}

// ---- workspace layout (bytes) ----
#define WS_EMB8  0u          // bf16 emb, 9792*4*2 = 78336
#define WS_W1T   78336u      // fragment-major bf16 w1*s1, 34*8192 = 278528
#define WS_W2F   356864u     // fragment-major bf16 w2*s2, 2048
#define WS_B1P   358912u     // f32 b1*s1+be1, 128
#define WS_B2P   359040u     // f32 b2*s2+be2, 128  (ws total ~359 KB)

// ---- LDS layout (bytes) for k_main ----
#define L_EMB  0             // 78336: bf16 emb table
#define L_NIB  78336         // 34816: 64 rows * 136 nib words
#define L_UNI  113152        // 37584: phase A: f32 wl[9396]
                             //        phase B: w1buf 2*16384; then part 8192 + h1b @+8192
#define L_W2   150736        // 2048
#define L_LIN  152784        // 256
#define L_TOT  153040

__global__ __launch_bounds__(256) void k0_setup(
    const float* __restrict__ emb, const float* __restrict__ w1,
    const float* __restrict__ b1, const float* __restrict__ g1,
    const float* __restrict__ be1, const float* __restrict__ w2,
    const float* __restrict__ b2, const float* __restrict__ g2,
    const float* __restrict__ be2, char* __restrict__ ws) {
  const float inv = 1.0f / sqrtf(1.0f + 1e-5f);
  const int idx = blockIdx.x * 256 + threadIdx.x;
  const int total = VOCP + NCHUNK*512 + 1024 + 64;   // 9792 + 17408 + 1024 + 64
  if (idx >= total) return;
  if (idx < VOCP) {
    int g = idx;
    float4 e = (g < 9396) ? ((const float4*)emb)[g] : make_float4(0.f,0.f,0.f,0.f);
    ushort4 u;
    u.x = bf16bits(e.x);
    u.y = bf16bits(e.y);
    u.z = bf16bits(e.z);
    u.w = bf16bits(e.w);
    *(ushort4*)(ws + WS_EMB8 + (size_t)g*8) = u;
  } else if (idx < VOCP + NCHUNK*512) {
    // one thread per 16-B fragment slot (c,s,kg,h)
    int m = idx - VOCP;
    int h = m & 31, kg = (m >> 5) & 3, s = (m >> 7) & 3, c = m >> 9;
    float s1 = g1[h] * inv;
    unsigned short v16[8];
    #pragma unroll
    for (int i = 0; i < 8; ++i) {
      int k = 128*c + 32*s + ((i < 4) ? (4*kg + i) : (16 + 4*kg + (i - 4)));
      float v = (k < 4176) ? w1[k*32 + h] * s1 : 0.0f;
      v16[i] = bf16bits(v);
    }
    int off = c*8192 + s*2048 + kg*512 + h*16;
    uint4 pk;
    __builtin_memcpy(&pk, v16, 16);
    *(uint4*)(ws + WS_W1T + off) = pk;
  } else if (idx < VOCP + NCHUNK*512 + 1024) {
    int m = idx - (VOCP + NCHUNK*512);
    int h = m >> 5, j = m & 31;
    float s2 = g2[j] * inv;
    float v = w2[h*32 + j] * s2;
    int half = h >> 4, kk = h & 15;
    int kg = kk >> 2, e = kk & 3;
    int off = kg*512 + j*16 + (half*4 + e)*2;
    *(__hip_bfloat16*)(ws + WS_W2F + off) = __float2bfloat16(v);
  } else {
    int m = idx - (VOCP + NCHUNK*512 + 1024);
    float* b1p = (float*)(ws + WS_B1P);
    float* b2p = (float*)(ws + WS_B2P);
    if (m < 32)      b1p[m]    = b1[m]*(g1[m]*inv) + be1[m];
    else             b2p[m-32] = b2[m-32]*(g2[m-32]*inv) + be2[m-32];
  }
}

__device__ __forceinline__ unsigned pack8(float4 a, float4 b) {
  float v[8] = {a.x, a.y, a.z, a.w, b.x, b.y, b.z, b.w};
  unsigned pk = 0;
  #pragma unroll
  for (int q = 0; q < 8; ++q) {
    int t = (v[q] > 5.0f) ? 8 : (int)(v[q] + 2.0f);
    pk |= (unsigned)t << (4*q);
  }
  return pk;
}

// fused: hash + lin + gather-GEMM MLP.  grid 256 x 512 (8 waves, 64 rows/block)
__global__ __launch_bounds__(512) void k_main(
    const float* __restrict__ state, const float* __restrict__ wlin,
    const float* __restrict__ blin, char* __restrict__ ws,
    const float* __restrict__ w3g, const float* __restrict__ b3g,
    float* __restrict__ out) {
  __shared__ __align__(16) char smem[L_TOT];
  const int t = threadIdx.x;
  const int lane = t & 63, w = t >> 6;
  const int rowbase = blockIdx.x * 64;

  // ---- stage tables (L2-hot, ~116 KB) ----
  float* wl = (float*)(smem + L_UNI);
  {
    const float4* src = (const float4*)wlin;
    float4* dst = (float4*)wl;
    for (int i = t; i < 2349; i += 512) dst[i] = src[i];
    const uint4* e = (const uint4*)(ws + WS_EMB8);
    uint4* ed = (uint4*)(smem + L_EMB);
    for (int i = t; i < 4896; i += 512) ed[i] = e[i];
    if (t < 128) ((uint4*)(smem + L_W2))[t] = ((const uint4*)(ws + WS_W2F))[t];
  }
  __syncthreads();

  // ---- phase A: hash -> nibbles(LDS) + lin(LDS) ----
  unsigned* nibL = (unsigned*)(smem + L_NIB);
  float* linL = (float*)(smem + L_LIN);
  const float bl = blin[0];
  const int l = lane;
  for (int ri = 0; ri < 8; ++ri) {
    const int rl = w*8 + ri;
    const float4* s4 = (const float4*)(state + (size_t)(rowbase + rl) * 1044);
    float4 a0 = s4[2*l],     b0 = s4[2*l + 1];
    float4 a1 = s4[128+2*l], b1 = s4[129+2*l];
    float4 zz = make_float4(0.f, 0.f, 0.f, 0.f);
    float4 ta = (l < 3) ? s4[256 + 2*l] : zz;     // fields 1024.. (word 130 half-valid)
    float4 tb = (l < 2) ? s4[257 + 2*l] : zz;
    unsigned pk0 = pack8(a0, b0);
    unsigned pk1 = pack8(a1, b1);
    unsigned pk2 = pack8(ta, tb);
    unsigned* nr = nibL + rl*NWORD;
    nr[l]      = pk0;
    nr[64 + l] = pk1;
    if (l < 8) nr[128 + l] = pk2;                 // words 128..135 (pad fields -> v=2, emb row 0)

    float lacc = 0.f;
    #pragma unroll
    for (int j = 0; j < 16; ++j) {
      int src = (l >> 3) + 8 * (j & 7);
      unsigned wv = __shfl((j < 8) ? pk0 : pk1, src, 64);
      int v = (wv >> (4 * (l & 7))) & 15;
      lacc += wl[(l + 64*j) * 9 + v];
    }
    if (l < 20) {                                  // fields 1024..1043
      unsigned wv = __shfl(pk2, l >> 3, 64);
      int v = (wv >> (4 * (l & 7))) & 15;
      lacc += wl[(l + 1024) * 9 + v];
    }
    #pragma unroll
    for (int m = 1; m < 64; m <<= 1) lacc += __shfl_xor(lacc, m, 64);
    if (l == 0) linL[rl] = lacc + bl;
  }
  __syncthreads();        // nib/lin visible; wl dead -> union becomes w1buf

  // ---- phase B: K-parity-split gather GEMM ----
  const uint4* w1g4 = (const uint4*)(ws + WS_W1T);
  uint4* w1buf = (uint4*)(smem + L_UNI);
  {   // super-chunk 0 (chunks 0,1)
    w1buf[t*2]     = w1g4[t*2];
    w1buf[t*2 + 1] = w1g4[t*2 + 1];
  }
  __syncthreads();

  const int rt = w & 3, kp = w >> 2;      // row-tile, chunk parity
  const int kg = lane >> 4, h = lane & 15;
  const int sh0 = 8*(kg >> 1);
  const int nibsel = kg & 1;
  const s16x4* E4 = (const s16x4*)(smem + L_EMB);
  const unsigned* nibrow = nibL + (rt*16 + h)*NWORD;
  f32x4 acc0 = {0.f,0.f,0.f,0.f}, acc1 = {0.f,0.f,0.f,0.f};

  for (int j = 0; j < 17; ++j) {
    uint4 st0 = {0,0,0,0}, st1 = {0,0,0,0};
    const bool more = (j + 1 < 17);
    if (more) {
      st0 = w1g4[(j+1)*1024 + t*2];
      st1 = w1g4[(j+1)*1024 + t*2 + 1];
    }
    const int c = 2*j + kp;
    const char* wb = (const char*)(w1buf + (j & 1)*1024) + kp*8192;
    uint4 nw = *(const uint4*)(nibrow + 4*c);
    unsigned nwa[4] = {nw.x, nw.y, nw.z, nw.w};
    #pragma unroll
    for (int s = 0; s < 4; ++s) {
      unsigned W = nwa[s];
      unsigned bA = (W >> sh0) & 0xFFu;
      unsigned bB = (W >> (sh0 + 16)) & 0xFFu;
      int vA = nibsel ? (int)(bA >> 4) : (int)(bA & 15u);
      int vB = nibsel ? (int)(bB >> 4) : (int)(bB & 15u);
      int F0 = c*32 + s*8 + kg;
      s16x4 e0 = E4[F0*9 + vA];
      s16x4 e1 = E4[(F0+4)*9 + vB];
      s16x8 a = __builtin_shufflevector(e0, e1, 0,1,2,3,4,5,6,7);
      const s16x8* bp = (const s16x8*)(wb + s*2048 + kg*512);
      s16x8 bf0 = bp[h];
      s16x8 bf1 = bp[h + 16];
      acc0 = __builtin_amdgcn_mfma_f32_16x16x32_bf16(a, bf0, acc0, 0, 0, 0);
      acc1 = __builtin_amdgcn_mfma_f32_16x16x32_bf16(a, bf1, acc1, 0, 0, 0);
    }
    if (more) {
      w1buf[((j+1) & 1)*1024 + t*2]     = st0;
      w1buf[((j+1) & 1)*1024 + t*2 + 1] = st1;
    }
    __syncthreads();
  }

  // ---- partial combine (odd-parity waves -> even-parity waves) ----
  float* part = (float*)(smem + L_UNI);                    // 8192 B
  __hip_bfloat16* h1b = (__hip_bfloat16*)(smem + L_UNI + 8192);  // 64*40 bf16
  if (kp == 1) {
    f32x4* pp = (f32x4*)(part + (rt*64 + lane)*8);
    pp[0] = acc0; pp[1] = acc1;
  }
  __syncthreads();
  if (kp == 0) {
    const f32x4* pp = (const f32x4*)(part + (rt*64 + lane)*8);
    f32x4 o0 = pp[0], o1 = pp[1];
    acc0 += o0; acc1 += o1;
    const float* b1p = (const float*)(ws + WS_B1P);
    const float bb0 = b1p[h], bb1 = b1p[h + 16];
    #pragma unroll
    for (int reg = 0; reg < 4; ++reg) {
      int r = kg*4 + reg;
      float a0 = acc0[reg] + bb0; a0 = a0 > 0.f ? a0 : 0.f;
      float a1 = acc1[reg] + bb1; a1 = a1 > 0.f ? a1 : 0.f;
      h1b[(rt*16 + r)*40 + h]      = __float2bfloat16(a0);
      h1b[(rt*16 + r)*40 + h + 16] = __float2bfloat16(a1);
    }
  }
  __syncthreads();
  if (kp == 0) {
    s16x4 alo = *(const s16x4*)&h1b[(rt*16 + h)*40 + kg*4];
    s16x4 ahi = *(const s16x4*)&h1b[(rt*16 + h)*40 + 16 + kg*4];
    s16x8 a2 = __builtin_shufflevector(alo, ahi, 0,1,2,3,4,5,6,7);
    const char* w2l = smem + L_W2;
    const s16x8* w2p8 = (const s16x8*)(w2l + kg*512);
    s16x8 b20 = w2p8[h];
    s16x8 b21 = w2p8[h + 16];
    f32x4 acc20 = {0.f,0.f,0.f,0.f}, acc21 = {0.f,0.f,0.f,0.f};
    acc20 = __builtin_amdgcn_mfma_f32_16x16x32_bf16(a2, b20, acc20, 0, 0, 0);
    acc21 = __builtin_amdgcn_mfma_f32_16x16x32_bf16(a2, b21, acc21, 0, 0, 0);
    const float* b2p = (const float*)(ws + WS_B2P);
    const float c20 = b2p[h], c21 = b2p[h + 16];
    const float w3a = w3g[h], w3b = w3g[h + 16];
    const float b3v = b3g[0];
    #pragma unroll
    for (int reg = 0; reg < 4; ++reg) {
      float h2a = acc20[reg] + c20; h2a = h2a > 0.f ? h2a : 0.f;
      float h2b = acc21[reg] + c21; h2b = h2b > 0.f ? h2b : 0.f;
      float p = h2a*w3a + h2b*w3b;
      p += __shfl_xor(p, 1);
      p += __shfl_xor(p, 2);
      p += __shfl_xor(p, 4);
      p += __shfl_xor(p, 8);
      if (h == 0) {
        int rl = rt*16 + kg*4 + reg;
        float x = p + linL[rl] + b3v;
        out[rowbase + rl] = 1.0f / (1.0f + expf(-x));
      }
    }
  }
}

extern "C" void kernel_launch(void* const* d_in, const int* in_sizes, int n_in,
                              void* d_out, int out_size, void* d_ws, size_t ws_size,
                              hipStream_t stream) {
  const float* state = (const float*)d_in[0];
  const float* wlin  = (const float*)d_in[1];
  const float* blin  = (const float*)d_in[2];
  const float* emb   = (const float*)d_in[3];
  const float* w1    = (const float*)d_in[4];
  const float* b1    = (const float*)d_in[5];
  const float* g1    = (const float*)d_in[6];
  const float* be1   = (const float*)d_in[7];
  const float* w2    = (const float*)d_in[8];
  const float* b2    = (const float*)d_in[9];
  const float* g2    = (const float*)d_in[10];
  const float* be2   = (const float*)d_in[11];
  const float* w3    = (const float*)d_in[12];
  const float* b3    = (const float*)d_in[13];
  char* ws = (char*)d_ws;
  float* out = (float*)d_out;

  hipLaunchKernelGGL(k0_setup, dim3(111), dim3(256), 0, stream,
                     emb, w1, b1, g1, be1, w2, b2, g2, be2, ws);
  hipLaunchKernelGGL(k_main, dim3(256), dim3(512), 0, stream,
                     state, wlin, blin, ws, w3, b3, out);
}